// Round 2
// baseline (697.758 us; speedup 1.0000x reference)
//
#include <hip/hip_runtime.h>
#include <hip/hip_bf16.h>

typedef __attribute__((ext_vector_type(4))) float float4v;
typedef __attribute__((ext_vector_type(8))) __bf16 bf16x8;
typedef __attribute__((ext_vector_type(4))) unsigned short ushort4v;

constexpr int NTOK = 50176;
constexpr int DIM  = 384;
constexpr int HID  = 1536;
constexpr int BM   = 128;
constexpr int NTH  = 512;
constexpr int NBLK = NTOK / BM;   // 392
constexpr int NCH  = 24;          // hidden chunks of 64

// workspace (byte offsets) — pre-swizzled bf16 images, gll-linear order
constexpr int IMG_WD  = 0;                  // [32][384] 768B rows, 24576 B
constexpr int IMG_WUP = 24576;              // [384][32] 64B rows,  24576 B
constexpr int IMG_W1  = 49152;              // 24 x [64][384] 768B rows, 49152 B each
constexpr int IMG_W2  = 49152 + 24*49152;   // 24 x [384][64] 128B rows
constexpr size_t WS_NEED = 2408448;         // same as proven-available R1 guard
constexpr int NELEMS = 1204224;             // total ushort elems

// LDS byte offsets
constexpr int L_W1 = 0;        // 48K
constexpr int L_W2 = 49152;    // 48K
constexpr int L_HS = 98304;    // 16K  [128][64] bf16, 128B rows, swizzled
constexpr int L_B1 = 114688;   // 6K   f32 bias1
constexpr int L_B2 = 120832;   // 1.5K f32 bias2
constexpr int LDSZ = 122368;

__device__ __forceinline__ unsigned short f2bf(float f) {
  __hip_bfloat16 h = __float2bfloat16(f);
  return *reinterpret_cast<unsigned short*>(&h);
}

__device__ __forceinline__ float gelu_f(float v) {
  float u = 0.7978845608f * (v + 0.044715f * v * v * v);
  float e = __expf(2.0f * u);
  float t = 1.0f - 2.0f / (e + 1.0f);
  return 0.5f * v * (1.0f + t);
}

__device__ __forceinline__ void gll16(const void* g, void* l) {
  __builtin_amdgcn_global_load_lds(
      (const __attribute__((address_space(1))) unsigned int*)g,
      (__attribute__((address_space(3))) unsigned int*)l, 16, 0, 0);
}

// copy perWave KiB-granules: wave-uniform LDS base + lane*16 (linear); image pre-swizzled
template<int PER_WAVE>
__device__ __forceinline__ void stage_img(const char* srcBase, char* dstBase, int wid, int lane) {
  const char* s = srcBase + wid * 1024 + lane * 16;
  char* d = dstBase + wid * 1024;
  #pragma unroll
  for (int j = 0; j < PER_WAVE; ++j)
    gll16(s + j * 8192, d + j * 8192);
}

// ---------------- pack kernel: f32 weights -> pre-swizzled bf16 images ----------------
__global__ __launch_bounds__(256) void pack_k(
    const float* __restrict__ W1, const float* __restrict__ W2,
    const float* __restrict__ wd, const float* __restrict__ wu,
    unsigned short* __restrict__ img)
{
  int i = blockIdx.x * 256 + threadIdx.x;
  if (i >= NELEMS) return;
  if (i < 12288) {                              // WD: rows r=lora-col (0..31), 768B rows
    int r = i / 384; int inb = (i % 384) * 2;
    int d = (inb ^ ((r & 7) << 4)) >> 1;
    float f = (r < 24) ? wd[(r >> 3) * (DIM * 8) + d * 8 + (r & 7)] : 0.f;
    img[i] = f2bf(f);
  } else if (i < 24576) {                       // WUP: [384 d][32 k], 64B rows, cross-row swz
    int j = i - 12288; int a = j * 2;
    int dh = a >> 7; int b6 = (a >> 6) & 1;
    int d = dh * 2 + (b6 ^ ((dh >> 1) & 1));
    int k = ((a & 63) ^ ((d & 3) << 4)) >> 1;
    float f = (k < 24) ? wu[k * DIM + d] : 0.f;
    img[i] = f2bf(f);
  } else if (i < 24576 + 589824) {              // W1 chunks: [64 F][384 d], 768B rows
    int j = i - 24576; int h = j / 24576; int jc = j % 24576;
    int r = jc / 384; int inb = (jc % 384) * 2;
    int d = (inb ^ ((r & 7) << 4)) >> 1;
    img[i] = f2bf(W1[d * HID + h * 64 + r]);
  } else {                                      // W2 chunks: [384 d][64 k], 128B rows
    int j = i - 24576 - 589824; int h = j / 24576; int jc = j % 24576;
    int dd = jc / 64; int inb = (jc % 64) * 2;
    int k2 = (inb ^ ((dd & 7) << 4)) >> 1;
    img[i] = f2bf(W2[(h * 64 + k2) * DIM + dd]);
  }
}

// ---------------- fused MLP + MoE-LoRA ----------------
__global__ __launch_bounds__(NTH, 2) void fused_k(
    const float* __restrict__ x,
    const float* __restrict__ tp,
    const int*   __restrict__ ti,
    const float* __restrict__ b1,
    const float* __restrict__ b2,
    const unsigned short* __restrict__ img,
    float* __restrict__ out)
{
  extern __shared__ char lds[];
  const int tid = threadIdx.x, wid = tid >> 6, lane = tid & 63;
  const int lrow = lane & 15, g4 = lane >> 4, lkb = g4 * 8;
  const int blockRow = blockIdx.x * BM;
  const char* imgc = (const char*)img;

  // ---- prologue: biases -> LDS ----
  for (int i = tid; i < HID; i += NTH) ((float*)(lds + L_B1))[i] = b1[i];
  if (tid < DIM) ((float*)(lds + L_B2))[tid] = b2[tid];

  // ---- X tile f32 -> bf16 -> LDS (swizzled, 768B rows) at base 0 (temp) ----
  {
    const float* xb = x + (size_t)blockRow * DIM;
    #pragma unroll
    for (int it = 0; it < 24; ++it) {
      int idx = it * NTH + tid;
      int row = idx / 96, c4 = idx % 96;
      float4v v = *(const float4v*)(xb + row * DIM + c4 * 4);
      ushort4v u; u[0]=f2bf(v[0]); u[1]=f2bf(v[1]); u[2]=f2bf(v[2]); u[3]=f2bf(v[3]);
      int byte = (row * 768 + c4 * 8) ^ ((row & 7) << 4);
      *(ushort4v*)(lds + byte) = u;
    }
  }
  __syncthreads();

  // ---- X A-fragments -> registers (persist across all chunks) ----
  const int band = wid >> 1, chh = wid & 1;     // G1 wave grid: 4 row-bands x 2 col-halves
  bf16x8 xf[2][12];
  #pragma unroll
  for (int mt = 0; mt < 2; ++mt) {
    int row = band * 32 + mt * 16 + lrow;
    int rb = row * 768, sw = (row & 7) << 4;
    #pragma unroll
    for (int ks = 0; ks < 12; ++ks)
      xf[mt][ks] = *(const bf16x8*)(lds + ((rb + (ks * 32 + lkb) * 2) ^ sw));
  }
  __syncthreads();   // all X reads done before gll overwrites

  // ---- MoE chunk: stage both small images ----
  stage_img<3>(imgc + IMG_WD,  lds + L_W1, wid, lane);
  stage_img<3>(imgc + IMG_WUP, lds + L_W2, wid, lane);
  __syncthreads();   // implicit vmcnt(0) drain -> WD/WUP ready

  // G1-moe: t1 = X @ WdT  -> [128][32]
  float4v h2[2] = {};
  {
    int rbw = chh * 16 + lrow, sww = (rbw & 7) << 4;
    #pragma unroll
    for (int ks = 0; ks < 12; ++ks) {
      bf16x8 b = *(const bf16x8*)(lds + L_W1 + ((rbw * 768 + (ks * 32 + lkb) * 2) ^ sww));
      h2[0] = __builtin_amdgcn_mfma_f32_16x16x32_bf16(xf[0][ks], b, h2[0], 0, 0, 0);
      h2[1] = __builtin_amdgcn_mfma_f32_16x16x32_bf16(xf[1][ks], b, h2[1], 0, 0, 0);
    }
  }
  // prob * gelu -> Hs cols 0..31
  {
    int col = chh * 16 + lrow; int e = col >> 3;
    #pragma unroll
    for (int mt = 0; mt < 2; ++mt) {
      #pragma unroll
      for (int r = 0; r < 4; ++r) {
        int row = band * 32 + mt * 16 + g4 * 4 + r;
        int token = blockRow + row;
        float p = 0.f;
        if (e < 3) {
          int i0 = ti[token * 2], i1 = ti[token * 2 + 1];
          if (i0 == e) p += tp[token * 2];
          if (i1 == e) p += tp[token * 2 + 1];
        }
        float gv = p * gelu_f(h2[mt][r]);
        int byte = (row * 128 + col * 2) ^ ((row & 7) << 4);
        *(unsigned short*)(lds + L_HS + byte) = f2bf(gv);
      }
    }
  }
  __syncthreads();   // Hs ready; G1-moe done with W1buf
  stage_img<6>(imgc + IMG_W1, lds + L_W1, wid, lane);   // gll W1[h=0], lands under G2-moe

  // G2-moe: acc += Hs(0..31) @ WupT  (K=32)
  const int wr = wid >> 2, wc = wid & 3;        // G2 wave grid: 2M x 4N
  float4v acc[4][6] = {};
  {
    bf16x8 A[4];
    #pragma unroll
    for (int mt = 0; mt < 4; ++mt) {
      int ra = wr * 64 + mt * 16 + lrow;
      A[mt] = *(const bf16x8*)(lds + L_HS + ((ra * 128 + lkb * 2) ^ ((ra & 7) << 4)));
    }
    #pragma unroll
    for (int nt = 0; nt < 6; ++nt) {
      int rb = wc * 96 + nt * 16 + lrow;
      bf16x8 b = *(const bf16x8*)(lds + L_W2 + ((rb * 64 + lkb * 2) ^ ((rb & 7) << 4)));
      #pragma unroll
      for (int mt = 0; mt < 4; ++mt)
        acc[mt][nt] = __builtin_amdgcn_mfma_f32_16x16x32_bf16(A[mt], b, acc[mt][nt], 0, 0, 0);
    }
  }

  // ---- main loop over 24 hidden chunks ----
  for (int h = 0; h < NCH; ++h) {
    __syncthreads();   // b1: drains gll W1[h]; all waves past G2(h-1) -> W2buf free
    stage_img<6>(imgc + IMG_W2 + h * 49152, lds + L_W2, wid, lane);  // lands under G1+GELU

    // G1: H = X @ W1c -> [128][64]; per-wave 32x32 tile, A from regs
    float4v hv[2][2] = {};
    {
      int r0 = chh * 32 + lrow, r1 = r0 + 16;
      int s0 = (r0 & 7) << 4, s1 = (r1 & 7) << 4;
      #pragma unroll
      for (int ks = 0; ks < 12; ++ks) {
        int ko = (ks * 32 + lkb) * 2;
        bf16x8 b0 = *(const bf16x8*)(lds + L_W1 + ((r0 * 768 + ko) ^ s0));
        bf16x8 b1v= *(const bf16x8*)(lds + L_W1 + ((r1 * 768 + ko) ^ s1));
        hv[0][0] = __builtin_amdgcn_mfma_f32_16x16x32_bf16(xf[0][ks], b0,  hv[0][0], 0, 0, 0);
        hv[0][1] = __builtin_amdgcn_mfma_f32_16x16x32_bf16(xf[0][ks], b1v, hv[0][1], 0, 0, 0);
        hv[1][0] = __builtin_amdgcn_mfma_f32_16x16x32_bf16(xf[1][ks], b0,  hv[1][0], 0, 0, 0);
        hv[1][1] = __builtin_amdgcn_mfma_f32_16x16x32_bf16(xf[1][ks], b1v, hv[1][1], 0, 0, 0);
      }
    }
    // bias + gelu -> Hs
    #pragma unroll
    for (int nt = 0; nt < 2; ++nt) {
      int col = chh * 32 + nt * 16 + lrow;
      float bb = ((const float*)(lds + L_B1))[h * 64 + col];
      #pragma unroll
      for (int mt = 0; mt < 2; ++mt) {
        #pragma unroll
        for (int r = 0; r < 4; ++r) {
          int row = band * 32 + mt * 16 + g4 * 4 + r;
          float gv = gelu_f(hv[mt][nt][r] + bb);
          int byte = (row * 128 + col * 2) ^ ((row & 7) << 4);
          *(unsigned short*)(lds + L_HS + byte) = f2bf(gv);
        }
      }
    }
    __syncthreads();   // b2: drains gll W2[h]; Hs ready; G1 done with W1buf
    if (h < NCH - 1)
      stage_img<6>(imgc + IMG_W1 + (h + 1) * 49152, lds + L_W1, wid, lane); // lands under G2

    // G2: acc += Hs @ W2c (K=64)
    #pragma unroll
    for (int kk = 0; kk < 2; ++kk) {
      int kb = kk * 32 + lkb;
      bf16x8 A[4];
      #pragma unroll
      for (int mt = 0; mt < 4; ++mt) {
        int ra = wr * 64 + mt * 16 + lrow;
        A[mt] = *(const bf16x8*)(lds + L_HS + ((ra * 128 + kb * 2) ^ ((ra & 7) << 4)));
      }
      #pragma unroll
      for (int nt = 0; nt < 6; ++nt) {
        int rb = wc * 96 + nt * 16 + lrow;
        bf16x8 b = *(const bf16x8*)(lds + L_W2 + ((rb * 128 + kb * 2) ^ ((rb & 7) << 4)));
        #pragma unroll
        for (int mt = 0; mt < 4; ++mt)
          acc[mt][nt] = __builtin_amdgcn_mfma_f32_16x16x32_bf16(A[mt], b, acc[mt][nt], 0, 0, 0);
      }
    }
  }

  // ---- epilogue: + b2, store f32 ----
  #pragma unroll
  for (int nt = 0; nt < 6; ++nt) {
    int col = wc * 96 + nt * 16 + lrow;
    float bb = ((const float*)(lds + L_B2))[col];
    #pragma unroll
    for (int mt = 0; mt < 4; ++mt) {
      #pragma unroll
      for (int r = 0; r < 4; ++r) {
        int row = wr * 64 + mt * 16 + g4 * 4 + r;
        out[(size_t)(blockRow + row) * DIM + col] = acc[mt][nt][r] + bb;
      }
    }
  }
}

extern "C" void kernel_launch(void* const* d_in, const int* in_sizes, int n_in,
                              void* d_out, int out_size, void* d_ws, size_t ws_size,
                              hipStream_t stream) {
  const float* x          = (const float*)d_in[0];
  const float* topk_probs = (const float*)d_in[2];
  const int*   topk_idx   = (const int*)  d_in[3];
  const float* w_down     = (const float*)d_in[4];
  const float* w_up       = (const float*)d_in[5];
  const float* W1         = (const float*)d_in[6];
  const float* b1         = (const float*)d_in[7];
  const float* W2         = (const float*)d_in[8];
  const float* b2         = (const float*)d_in[9];
  float* out = (float*)d_out;

  if (ws_size < WS_NEED) return;

  hipFuncSetAttribute(reinterpret_cast<const void*>(fused_k),
                      hipFuncAttributeMaxDynamicSharedMemorySize, LDSZ);

  unsigned short* img = (unsigned short*)d_ws;
  pack_k<<<(NELEMS + 255) / 256, 256, 0, stream>>>(W1, W2, w_down, w_up, img);
  fused_k<<<NBLK, NTH, LDSZ, stream>>>(x, topk_probs, topk_idx, b1, b2, img, out);
}